// Round 5
// baseline (403.134 us; speedup 1.0000x reference)
//
#include <hip/hip_runtime.h>
#include <stdint.h>

#define BB 4
#define NN 32768
#define PRE 4096
#define POST 512
#define NMS_TH 0.7f
#define MIDCAP 8192

typedef unsigned long long u64;
typedef unsigned int u32;

__device__ __forceinline__ u32 orderable(float f) {
  u32 u = __float_as_uint(f);
  return (u & 0x80000000u) ? ~u : (u | 0x80000000u);
}
__device__ __forceinline__ float unorderable(u32 o) {
  u32 u = (o & 0x80000000u) ? (o & 0x7fffffffu) : ~o;
  return __uint_as_float(u);
}
// Monotone fixed-point bucket: uniform in score space (scores in [0,1)).
// float*2^31 is monotone; u32 cast truncates (saturates at 0 for negatives);
// clamp handles s values whose product rounds up to 2^31.
__device__ __forceinline__ u32 bucket_of(float s) {
  u32 v = (u32)(s * 2147483648.0f);
  u32 bk = v >> 20;
  return bk > 2047u ? 2047u : bk;
}

// Zero the histogram + atomic counters (ws is not re-poisoned between replays).
__global__ void zero_kernel(u32* __restrict__ hist, u32* __restrict__ cnt_hi,
                            u32* __restrict__ cnt_mid) {
  int t = blockIdx.x * 256 + threadIdx.x;
  if (t < BB * 2048) hist[t] = 0;
  if (t < BB) { cnt_hi[t] = 0; cnt_mid[t] = 0; }
}

// score = max over 3 classes, label = first argmax, key = orderable(score)||~idx.
// Histogram fixed-point bucket per batch.
__global__ __launch_bounds__(256) void score_hist_kernel(const float* __restrict__ cls,
                                                         int* __restrict__ labels,
                                                         u64* __restrict__ keys,
                                                         u32* __restrict__ hist) {
  __shared__ u32 lh[2048];
  for (int t = threadIdx.x; t < 2048; t += 256) lh[t] = 0;
  __syncthreads();
  int g = blockIdx.x * 256 + threadIdx.x;           // BB*NN is an exact multiple of 256
  const float* c = cls + (size_t)g * 3;
  float s = c[0]; int l = 0;
  float c1 = c[1], c2 = c[2];
  if (c1 > s) { s = c1; l = 1; }
  if (c2 > s) { s = c2; l = 2; }
  int n = g & (NN - 1);
  keys[g] = ((u64)orderable(s) << 32) | (u32)(~(u32)n);
  labels[g] = l;
  atomicAdd(&lh[bucket_of(s)], 1u);
  __syncthreads();
  int b = blockIdx.x >> 7;                           // 128 blocks per batch
  for (int t = threadIdx.x; t < 2048; t += 256) {
    u32 v = lh[t];
    if (v) atomicAdd(&hist[b * 2048 + t], v);
  }
}

// Per batch: suffix-scan the 2048-bucket histogram, find threshold bucket T with
// count(>T) < PRE <= count(>=T). selinfo[b] = {T, C1=count(>T)}.
__global__ __launch_bounds__(256) void select_kernel(const u32* __restrict__ hist,
                                                     u32* __restrict__ selinfo) {
  __shared__ u32 sfx[2048];
  int b = blockIdx.x;
  for (int t = threadIdx.x; t < 2048; t += 256) sfx[t] = hist[b * 2048 + t];
  __syncthreads();
  for (int d = 1; d < 2048; d <<= 1) {
    u32 v[8];
#pragma unroll
    for (int i = 0; i < 8; ++i) {
      int t = threadIdx.x + i * 256;
      v[i] = (t + d < 2048) ? sfx[t + d] : 0;
    }
    __syncthreads();
#pragma unroll
    for (int i = 0; i < 8; ++i) sfx[threadIdx.x + i * 256] += v[i];
    __syncthreads();
  }
  for (int t = threadIdx.x; t < 2048; t += 256) {
    u32 above = (t + 1 < 2048) ? sfx[t + 1] : 0;
    if (above < PRE && sfx[t] >= PRE) { selinfo[b * 2] = (u32)t; selinfo[b * 2 + 1] = above; }
  }
}

// Compact: bucket > T -> sel[0..C1) (order-free; final sort restores order);
// bucket == T -> mid buffer for exact tie-breaking. Bucket recomputed from the
// score bits inside the key (exact roundtrip -> same bucket as histogram).
__global__ __launch_bounds__(256) void compact_kernel(const u64* __restrict__ keys,
                                                      const u32* __restrict__ selinfo,
                                                      u64* __restrict__ sel, u64* __restrict__ mid,
                                                      u32* __restrict__ cnt_hi,
                                                      u32* __restrict__ cnt_mid) {
  int g = blockIdx.x * 256 + threadIdx.x;
  int b = g >> 15;
  u64 key = keys[g];
  u32 bk = bucket_of(unorderable((u32)(key >> 32)));
  u32 T = selinfo[b * 2];
  if (bk > T) {
    u32 p = atomicAdd(&cnt_hi[b], 1u);
    sel[((size_t)b << 12) + p] = key;
  } else if (bk == T) {
    u32 p = atomicAdd(&cnt_mid[b], 1u);
    if (p < MIDCAP) mid[(size_t)b * MIDCAP + p] = key;   // ~45 expected with this data
  }
}

// Pick the top (PRE-C1) keys from the threshold bucket by repeated wave argmax
// (need ~ 25 with this data). Writes sel[C1..PRE).
__global__ __launch_bounds__(64) void midsel_kernel(u64* __restrict__ mid,
                                                    const u32* __restrict__ selinfo,
                                                    const u32* __restrict__ cnt_mid,
                                                    u64* __restrict__ sel) {
  int b = blockIdx.x;
  int lane = threadIdx.x;
  u32 C1 = selinfo[b * 2 + 1];
  int need = PRE - (int)C1;
  int M = (int)cnt_mid[b]; if (M > MIDCAP) M = MIDCAP;
  for (int r = 0; r < need; ++r) {
    u64 best = 0; int bi = -1;
    for (int t = lane; t < M; t += 64) {
      u64 v = mid[(size_t)b * MIDCAP + t];
      if (v > best) { best = v; bi = t; }
    }
#pragma unroll
    for (int d = 32; d > 0; d >>= 1) {
      u64 ob = __shfl_xor(best, d, 64);
      int oi = __shfl_xor(bi, d, 64);
      if (ob > best) { best = ob; bi = oi; }
    }
    if (lane == 0) sel[((size_t)b << 12) + C1 + r] = best;
    if (bi >= 0 && lane == (bi & 63)) mid[(size_t)b * MIDCAP + bi] = 0;  // remove chosen
  }
}

// Full descending bitonic sort of one 4096-chunk in LDS (unique keys -> total order).
__global__ __launch_bounds__(512) void sort4k_kernel(u64* keys) {
  __shared__ u64 sh[4096];
  u64* base = keys + (size_t)blockIdx.x * 4096;
  for (int t = threadIdx.x; t < 4096; t += 512) sh[t] = base[t];
  __syncthreads();
  for (int k = 2; k <= 4096; k <<= 1) {
    for (int j = k >> 1; j > 0; j >>= 1) {
      for (int t = threadIdx.x; t < 4096; t += 512) {
        int p = t ^ j;
        if (p > t) {
          u64 a = sh[t], b = sh[p];
          bool desc = ((t & k) == 0);
          if (desc ? (a < b) : (a > b)) { sh[t] = b; sh[p] = a; }
        }
      }
      __syncthreads();
    }
  }
  for (int t = threadIdx.x; t < 4096; t += 512) base[t] = sh[t];
}

// Gather top-4096 boxes; pack bounds as float4 + area; recover score from key bits.
__global__ void gather_kernel(const u64* __restrict__ keys, const float* __restrict__ boxes,
                              const int* __restrict__ labels,
                              float* __restrict__ topBox, float4* __restrict__ P,
                              float* __restrict__ AR,
                              float* __restrict__ topS, int* __restrict__ topL) {
  int g = blockIdx.x * blockDim.x + threadIdx.x;
  if (g >= BB * PRE) return;
  int b = g >> 12;
  u64 key = keys[g];
  u32 n = ~(u32)key;
  size_t src = (size_t)b * NN + n;
  const float* bx = boxes + src * 7;
  float x = bx[0], y = bx[1], dx = bx[3], dy = bx[4];
  float* tb = topBox + (size_t)g * 7;
#pragma unroll
  for (int c = 0; c < 7; ++c) tb[c] = bx[c];
  float4 p;
  p.x = x - 0.5f * dx; p.z = x + 0.5f * dx;   // 0.5*dx exact -> contraction-safe
  p.y = y - 0.5f * dy; p.w = y + 0.5f * dy;
  P[g] = p;
  AR[g] = dx * dy;
  topS[g] = unorderable((u32)(key >> 32));
  topL[g] = labels[src];
}

// Ballot-form suppression mask. One wave per 64x64 tile; lane = column.
// Row k's values broadcast by shfl; word = __ballot(sup). Divide eliminated by
// inter > 0.7*denom with a conservative marginal band; wave falls back to the
// exact IEEE divide if any lane is within the band (bitwise == numpy).
__global__ __launch_bounds__(64) void mask_kernel(const float4* __restrict__ P,
                                                  const float* __restrict__ AR,
                                                  u64* __restrict__ mask,
                                                  u64* __restrict__ diag) {
  int w = blockIdx.x;         // column word 0..63
  int rb = blockIdx.y;        // row block 0..63
  int b = blockIdx.z;
  if (w < rb) return;         // strictly-below-diagonal tile: dead for the scan
  int lane = threadIdx.x;
  int base = b << 12;
  float4 cp = P[base + (w << 6) + lane];    // this lane's column box
  float car = AR[base + (w << 6) + lane];
  float4 rp = P[base + (rb << 6) + lane];   // this lane's row box (shfl source)
  float rar = AR[base + (rb << 6) + lane];
  u64 myword = 0;
#pragma unroll
  for (int k = 0; k < 64; ++k) {
    float bx1 = __shfl(rp.x, k, 64);
    float by1 = __shfl(rp.y, k, 64);
    float bx2 = __shfl(rp.z, k, 64);
    float by2 = __shfl(rp.w, k, 64);
    float bar = __shfl(rar, k, 64);
    float ix = fminf(bx2, cp.z) - fmaxf(bx1, cp.x); ix = fmaxf(0.0f, ix);
    float iy = fminf(by2, cp.w) - fmaxf(by1, cp.y); iy = fmaxf(0.0f, iy);
    float inter = ix * iy;
    float denom = ((bar + car) - inter) + 1e-6f;     // same op order as reference
    float t = 0.7f * denom;                          // denom >= 1 here, t > 0
    bool sup;
    bool marginal = fabsf(inter - t) <= 2e-5f * t;   // band >> max rounding skew (~4e-7)
    if (__any(marginal)) sup = (inter / denom) > NMS_TH;  // exact IEEE path
    else sup = inter > t;
    u64 word = __ballot(sup);
    if (lane == k) myword = word;
  }
  int row = (rb << 6) + lane;
  mask[(size_t)(base + row) * 64 + w] = myword;
  if (w == rb) diag[base + row] = myword;
}

// Greedy scan, group-of-64 formulation. One wave per batch.
__global__ __launch_bounds__(64) void scan_kernel(const u64* __restrict__ mask,
                                                  const u64* __restrict__ diag,
                                                  int* __restrict__ keepIdx,
                                                  int* __restrict__ keepCount) {
  __shared__ u64 kwLDS[64];
  int b = blockIdx.x;
  int lane = threadIdx.x;
  const u64* m = mask + (size_t)b * PRE * 64;
  const u64* dg = diag + (size_t)b * PRE;
  kwLDS[lane] = 0;
  __syncthreads();
  u64 r = 0;
  int nk = 0;
  for (int g = 0; g < PRE / 64; ++g) {
    u64 d_l = dg[g * 64 + lane];
    u64 rowv[64];
#pragma unroll
    for (int t = 0; t < 64; ++t) rowv[t] = m[((size_t)(g * 64 + t)) * 64 + lane];
    u64 sup_word = __shfl(r, g, 64);
    u64 keep_word = 0;
#pragma unroll
    for (int s = 0; s < 8; ++s) {
      u64 dk[8];
#pragma unroll
      for (int t = 0; t < 8; ++t) dk[t] = __shfl(d_l, s * 8 + t, 64);
#pragma unroll
      for (int t = 0; t < 8; ++t) {
        int k = s * 8 + t;
        u64 bit = (sup_word >> k) & 1ULL;
        keep_word |= (bit ^ 1ULL) << k;
        u64 mk = dk[t] & ~((2ULL << k) - 1ULL);
        sup_word |= mk & (bit - 1ULL);
      }
    }
    u64 acc = 0;
#pragma unroll
    for (int t = 0; t < 64; ++t)
      acc |= ((keep_word >> t) & 1ULL) ? rowv[t] : 0ULL;
    r |= acc;
    if (lane == 0) kwLDS[g] = keep_word;
    nk += __popcll(keep_word);
    if (nk >= POST) break;
  }
  __syncthreads();
  u64 kw = kwLDS[lane];
  int cnt = __popcll(kw);
  int pfx = cnt;
#pragma unroll
  for (int d = 1; d < 64; d <<= 1) {
    int up = __shfl_up(pfx, d, 64);
    if (lane >= d) pfx += up;
  }
  int total = __shfl(pfx, 63, 64);
  int pos = pfx - cnt;
  while (kw) {
    int t = __ffsll((long long)kw) - 1;
    kw &= kw - 1;
    if (pos < POST) keepIdx[b * POST + pos] = lane * 64 + t;
    ++pos;
  }
  if (lane == 0) keepCount[b] = total < POST ? total : POST;
}

// Write all 512 slots per batch: kept -> data, empty -> 0 (label 1).
__global__ void output_kernel(const int* __restrict__ keepIdx, const int* __restrict__ keepCount,
                              const float* __restrict__ topBox, const float* __restrict__ topS,
                              const int* __restrict__ topL, float* __restrict__ out) {
  int g = blockIdx.x * blockDim.x + threadIdx.x;
  if (g >= BB * POST) return;
  int b = g >> 9, s = g & (POST - 1);
  float* outR = out;
  float* outS = out + BB * POST * 7;
  float* outL = outS + BB * POST;
  int cnt = keepCount[b];
  if (s < cnt) {
    int i = keepIdx[g];
    const float* tb = topBox + ((size_t)(b << 12) + i) * 7;
#pragma unroll
    for (int c = 0; c < 7; ++c) outR[(size_t)g * 7 + c] = tb[c];
    outS[g] = topS[(b << 12) + i];
    outL[g] = (float)(topL[(b << 12) + i] + 1);
  } else {
#pragma unroll
    for (int c = 0; c < 7; ++c) outR[(size_t)g * 7 + c] = 0.0f;
    outS[g] = 0.0f;
    outL[g] = 1.0f;
  }
}

extern "C" void kernel_launch(void* const* d_in, const int* in_sizes, int n_in,
                              void* d_out, int out_size, void* d_ws, size_t ws_size,
                              hipStream_t stream) {
  const float* boxes = (const float*)d_in[0];   // (4,32768,7)
  const float* cls   = (const float*)d_in[1];   // (4,32768,3)
  float* out = (float*)d_out;

  // ---- workspace carve-up (~11 MB) ----
  char* p = (char*)d_ws;
  auto take = [&](size_t bytes) { char* r = p; p += (bytes + 255) & ~(size_t)255; return (void*)r; };
  u64*   keys    = (u64*)  take((size_t)BB * NN * 8);
  int*   labels  = (int*)  take((size_t)BB * NN * 4);
  u32*   hist    = (u32*)  take((size_t)BB * 2048 * 4);
  u32*   selinfo = (u32*)  take((size_t)BB * 2 * 4);
  u32*   cnt_hi  = (u32*)  take((size_t)BB * 4);
  u32*   cnt_mid = (u32*)  take((size_t)BB * 4);
  u64*   sel     = (u64*)  take((size_t)BB * PRE * 8);
  u64*   mid     = (u64*)  take((size_t)BB * MIDCAP * 8);
  float* topBox  = (float*)take((size_t)BB * PRE * 7 * 4);
  float4* Pb     = (float4*)take((size_t)BB * PRE * 16);
  float* AR      = (float*)take((size_t)BB * PRE * 4);
  float* topS    = (float*)take((size_t)BB * PRE * 4);
  int*   topL    = (int*)  take((size_t)BB * PRE * 4);
  u64*   maskBuf = (u64*)  take((size_t)BB * PRE * 64 * 8);
  u64*   diagBuf = (u64*)  take((size_t)BB * PRE * 8);
  int*   keepIdx = (int*)  take((size_t)BB * POST * 4);
  int*   keepCnt = (int*)  take((size_t)BB * 4);

  zero_kernel<<<32, 256, 0, stream>>>(hist, cnt_hi, cnt_mid);
  score_hist_kernel<<<BB * NN / 256, 256, 0, stream>>>(cls, labels, keys, hist);
  select_kernel<<<BB, 256, 0, stream>>>(hist, selinfo);
  compact_kernel<<<BB * NN / 256, 256, 0, stream>>>(keys, selinfo, sel, mid, cnt_hi, cnt_mid);
  midsel_kernel<<<BB, 64, 0, stream>>>(mid, selinfo, cnt_mid, sel);
  sort4k_kernel<<<BB, 512, 0, stream>>>(sel);
  gather_kernel<<<(BB * PRE + 255) / 256, 256, 0, stream>>>(sel, boxes, labels,
                                                            topBox, Pb, AR, topS, topL);
  mask_kernel<<<dim3(64, 64, BB), 64, 0, stream>>>(Pb, AR, maskBuf, diagBuf);
  scan_kernel<<<BB, 64, 0, stream>>>(maskBuf, diagBuf, keepIdx, keepCnt);
  output_kernel<<<(BB * POST + 255) / 256, 256, 0, stream>>>(keepIdx, keepCnt, topBox, topS, topL, out);
}

// Round 6
// 222.019 us; speedup vs baseline: 1.8158x; 1.8158x over previous
//
#include <hip/hip_runtime.h>
#include <stdint.h>

#define BB 4
#define NN 32768
#define PRE 4096
#define POST 512
#define NMS_TH 0.7f
#define MIDCAP 8192

typedef unsigned long long u64;
typedef unsigned int u32;

__device__ __forceinline__ u32 orderable(float f) {
  u32 u = __float_as_uint(f);
  return (u & 0x80000000u) ? ~u : (u | 0x80000000u);
}
__device__ __forceinline__ float unorderable(u32 o) {
  u32 u = (o & 0x80000000u) ? (o & 0x7fffffffu) : ~o;
  return __uint_as_float(u);
}
// Monotone fixed-point bucket: uniform in score space (scores in [0,1)).
__device__ __forceinline__ u32 bucket_of(float s) {
  u32 v = (u32)(s * 2147483648.0f);
  u32 bk = v >> 20;
  return bk > 2047u ? 2047u : bk;
}

// Zero the histogram + atomic counters (ws is not re-poisoned between replays).
__global__ void zero_kernel(u32* __restrict__ hist, u32* __restrict__ cnt_hi,
                            u32* __restrict__ cnt_mid) {
  int t = blockIdx.x * 256 + threadIdx.x;
  if (t < BB * 2048) hist[t] = 0;
  if (t < BB) { cnt_hi[t] = 0; cnt_mid[t] = 0; }
}

// score = max over 3 classes, label = first argmax, key = orderable(score)||~idx.
// Histogram fixed-point bucket per batch.
__global__ __launch_bounds__(256) void score_hist_kernel(const float* __restrict__ cls,
                                                         int* __restrict__ labels,
                                                         u64* __restrict__ keys,
                                                         u32* __restrict__ hist) {
  __shared__ u32 lh[2048];
  for (int t = threadIdx.x; t < 2048; t += 256) lh[t] = 0;
  __syncthreads();
  int g = blockIdx.x * 256 + threadIdx.x;           // BB*NN is an exact multiple of 256
  const float* c = cls + (size_t)g * 3;
  float s = c[0]; int l = 0;
  float c1 = c[1], c2 = c[2];
  if (c1 > s) { s = c1; l = 1; }
  if (c2 > s) { s = c2; l = 2; }
  int n = g & (NN - 1);
  keys[g] = ((u64)orderable(s) << 32) | (u32)(~(u32)n);
  labels[g] = l;
  atomicAdd(&lh[bucket_of(s)], 1u);
  __syncthreads();
  int b = blockIdx.x >> 7;                           // 128 blocks per batch
  for (int t = threadIdx.x; t < 2048; t += 256) {
    u32 v = lh[t];
    if (v) atomicAdd(&hist[b * 2048 + t], v);
  }
}

// Per batch: suffix-scan the 2048-bucket histogram, find threshold bucket T with
// count(>T) < PRE <= count(>=T). selinfo[b] = {T, C1=count(>T)}.
__global__ __launch_bounds__(256) void select_kernel(const u32* __restrict__ hist,
                                                     u32* __restrict__ selinfo) {
  __shared__ u32 sfx[2048];
  int b = blockIdx.x;
  for (int t = threadIdx.x; t < 2048; t += 256) sfx[t] = hist[b * 2048 + t];
  __syncthreads();
  for (int d = 1; d < 2048; d <<= 1) {
    u32 v[8];
#pragma unroll
    for (int i = 0; i < 8; ++i) {
      int t = threadIdx.x + i * 256;
      v[i] = (t + d < 2048) ? sfx[t + d] : 0;
    }
    __syncthreads();
#pragma unroll
    for (int i = 0; i < 8; ++i) sfx[threadIdx.x + i * 256] += v[i];
    __syncthreads();
  }
  for (int t = threadIdx.x; t < 2048; t += 256) {
    u32 above = (t + 1 < 2048) ? sfx[t + 1] : 0;
    if (above < PRE && sfx[t] >= PRE) { selinfo[b * 2] = (u32)t; selinfo[b * 2 + 1] = above; }
  }
}

// Compact, block-aggregated: 64 blocks x 256 threads x 8 keys. One atomicAdd per
// block per counter (Guideline 12) instead of per-wave same-address contention.
// Order within sel is arbitrary; sort4k restores total order.
__global__ __launch_bounds__(256) void compact_kernel(const u64* __restrict__ keys,
                                                      const u32* __restrict__ selinfo,
                                                      u64* __restrict__ sel, u64* __restrict__ mid,
                                                      u32* __restrict__ cnt_hi,
                                                      u32* __restrict__ cnt_mid) {
  __shared__ u32 wsum[4];
  __shared__ u32 baseSh[2];
  int blk = blockIdx.x;                 // 64 blocks; 16 per batch
  int b = blk >> 4;
  size_t eb = (size_t)blk * 2048;
  int tid = threadIdx.x;
  int lane = tid & 63, wv = tid >> 6;
  u32 T = selinfo[b * 2];
  u64 v[8];
  u32 flags = 0;
  u32 cH = 0, cM = 0;
#pragma unroll
  for (int c = 0; c < 8; ++c) {
    u64 k = keys[eb + c * 256 + tid];
    v[c] = k;
    u32 bk = bucket_of(unorderable((u32)(k >> 32)));
    if (bk > T) { flags |= 1u << c; ++cH; }
    else if (bk == T) { flags |= 1u << (c + 8); ++cM; }
  }
  u32 packed = (cH << 16) | cM;
  u32 pfx = packed;                      // wave inclusive prefix
#pragma unroll
  for (int d = 1; d < 64; d <<= 1) {
    u32 o = __shfl_up(pfx, d, 64);
    if (lane >= d) pfx += o;
  }
  if (lane == 63) wsum[wv] = pfx;
  __syncthreads();
  u32 waveBase = 0;
#pragma unroll
  for (int wq = 0; wq < 4; ++wq) waveBase += (wq < wv) ? wsum[wq] : 0;
  if (tid == 0) {
    u32 totals = wsum[0] + wsum[1] + wsum[2] + wsum[3];
    u32 tH = totals >> 16, tM = totals & 0xffffu;
    baseSh[0] = tH ? atomicAdd(&cnt_hi[b], tH) : 0u;
    baseSh[1] = tM ? atomicAdd(&cnt_mid[b], tM) : 0u;
  }
  __syncthreads();
  u32 exc = waveBase + pfx - packed;     // block-exclusive prefix
  u32 posH = baseSh[0] + (exc >> 16);
  u32 posM = baseSh[1] + (exc & 0xffffu);
  u64* selB = sel + ((size_t)b << 12);
  u64* midB = mid + (size_t)b * MIDCAP;
#pragma unroll
  for (int c = 0; c < 8; ++c) {
    if (flags & (1u << c)) selB[posH++] = v[c];
    else if (flags & (1u << (c + 8))) { if (posM < MIDCAP) midB[posM] = v[c]; ++posM; }
  }
}

// Pick the top (PRE-C1) keys from the threshold bucket by repeated wave argmax
// (need ~ 25 with this data). Writes sel[C1..PRE).
__global__ __launch_bounds__(64) void midsel_kernel(u64* __restrict__ mid,
                                                    const u32* __restrict__ selinfo,
                                                    const u32* __restrict__ cnt_mid,
                                                    u64* __restrict__ sel) {
  int b = blockIdx.x;
  int lane = threadIdx.x;
  u32 C1 = selinfo[b * 2 + 1];
  int need = PRE - (int)C1;
  int M = (int)cnt_mid[b]; if (M > MIDCAP) M = MIDCAP;
  for (int r = 0; r < need; ++r) {
    u64 best = 0; int bi = -1;
    for (int t = lane; t < M; t += 64) {
      u64 v = mid[(size_t)b * MIDCAP + t];
      if (v > best) { best = v; bi = t; }
    }
#pragma unroll
    for (int d = 32; d > 0; d >>= 1) {
      u64 ob = __shfl_xor(best, d, 64);
      int oi = __shfl_xor(bi, d, 64);
      if (ob > best) { best = ob; bi = oi; }
    }
    if (lane == 0) sel[((size_t)b << 12) + C1 + r] = best;
    if (bi >= 0 && lane == (bi & 63)) mid[(size_t)b * MIDCAP + bi] = 0;  // remove chosen
  }
}

// Full descending bitonic sort of one 4096-chunk in LDS (unique keys -> total order).
__global__ __launch_bounds__(512) void sort4k_kernel(u64* keys) {
  __shared__ u64 sh[4096];
  u64* base = keys + (size_t)blockIdx.x * 4096;
  for (int t = threadIdx.x; t < 4096; t += 512) sh[t] = base[t];
  __syncthreads();
  for (int k = 2; k <= 4096; k <<= 1) {
    for (int j = k >> 1; j > 0; j >>= 1) {
      for (int t = threadIdx.x; t < 4096; t += 512) {
        int p = t ^ j;
        if (p > t) {
          u64 a = sh[t], b = sh[p];
          bool desc = ((t & k) == 0);
          if (desc ? (a < b) : (a > b)) { sh[t] = b; sh[p] = a; }
        }
      }
      __syncthreads();
    }
  }
  for (int t = threadIdx.x; t < 4096; t += 512) base[t] = sh[t];
}

// Gather top-4096 boxes; pack bounds as float4 + area; recover score from key bits.
__global__ void gather_kernel(const u64* __restrict__ keys, const float* __restrict__ boxes,
                              const int* __restrict__ labels,
                              float* __restrict__ topBox, float4* __restrict__ P,
                              float* __restrict__ AR,
                              float* __restrict__ topS, int* __restrict__ topL) {
  int g = blockIdx.x * blockDim.x + threadIdx.x;
  if (g >= BB * PRE) return;
  int b = g >> 12;
  u64 key = keys[g];
  u32 n = ~(u32)key;
  size_t src = (size_t)b * NN + n;
  const float* bx = boxes + src * 7;
  float x = bx[0], y = bx[1], dx = bx[3], dy = bx[4];
  float* tb = topBox + (size_t)g * 7;
#pragma unroll
  for (int c = 0; c < 7; ++c) tb[c] = bx[c];
  float4 p;
  p.x = x - 0.5f * dx; p.z = x + 0.5f * dx;   // 0.5*dx exact -> contraction-safe
  p.y = y - 0.5f * dy; p.w = y + 0.5f * dy;
  P[g] = p;
  AR[g] = dx * dy;
  topS[g] = unorderable((u32)(key >> 32));
  topL[g] = labels[src];
}

// Ballot-form suppression mask. One wave per 64x64 tile; lane = column.
// Row k's values broadcast by shfl; word = __ballot(sup). Divide eliminated by
// inter > 0.7*denom with a conservative marginal band; wave falls back to the
// exact IEEE divide if any lane is within the band (bitwise == numpy).
__global__ __launch_bounds__(64) void mask_kernel(const float4* __restrict__ P,
                                                  const float* __restrict__ AR,
                                                  u64* __restrict__ mask,
                                                  u64* __restrict__ diag) {
  int w = blockIdx.x;         // column word 0..63
  int rb = blockIdx.y;        // row block 0..63
  int b = blockIdx.z;
  if (w < rb) return;         // strictly-below-diagonal tile: dead for the scan
  int lane = threadIdx.x;
  int base = b << 12;
  float4 cp = P[base + (w << 6) + lane];    // this lane's column box
  float car = AR[base + (w << 6) + lane];
  float4 rp = P[base + (rb << 6) + lane];   // this lane's row box (shfl source)
  float rar = AR[base + (rb << 6) + lane];
  u64 myword = 0;
#pragma unroll
  for (int k = 0; k < 64; ++k) {
    float bx1 = __shfl(rp.x, k, 64);
    float by1 = __shfl(rp.y, k, 64);
    float bx2 = __shfl(rp.z, k, 64);
    float by2 = __shfl(rp.w, k, 64);
    float bar = __shfl(rar, k, 64);
    float ix = fminf(bx2, cp.z) - fmaxf(bx1, cp.x); ix = fmaxf(0.0f, ix);
    float iy = fminf(by2, cp.w) - fmaxf(by1, cp.y); iy = fmaxf(0.0f, iy);
    float inter = ix * iy;
    float denom = ((bar + car) - inter) + 1e-6f;     // same op order as reference
    float t = 0.7f * denom;                          // denom >= 1 here, t > 0
    bool sup;
    bool marginal = fabsf(inter - t) <= 2e-5f * t;   // band >> max rounding skew (~4e-7)
    if (__any(marginal)) sup = (inter / denom) > NMS_TH;  // exact IEEE path
    else sup = inter > t;
    u64 word = __ballot(sup);
    if (lane == k) myword = word;
  }
  int row = (rb << 6) + lane;
  mask[(size_t)(base + row) * 64 + w] = myword;
  if (w == rb) diag[base + row] = myword;
}

// Greedy scan, group-of-64 formulation. One wave per batch.
__global__ __launch_bounds__(64) void scan_kernel(const u64* __restrict__ mask,
                                                  const u64* __restrict__ diag,
                                                  int* __restrict__ keepIdx,
                                                  int* __restrict__ keepCount) {
  __shared__ u64 kwLDS[64];
  int b = blockIdx.x;
  int lane = threadIdx.x;
  const u64* m = mask + (size_t)b * PRE * 64;
  const u64* dg = diag + (size_t)b * PRE;
  kwLDS[lane] = 0;
  __syncthreads();
  u64 r = 0;
  int nk = 0;
  for (int g = 0; g < PRE / 64; ++g) {
    u64 d_l = dg[g * 64 + lane];
    u64 rowv[64];
#pragma unroll
    for (int t = 0; t < 64; ++t) rowv[t] = m[((size_t)(g * 64 + t)) * 64 + lane];
    u64 sup_word = __shfl(r, g, 64);
    u64 keep_word = 0;
#pragma unroll
    for (int s = 0; s < 8; ++s) {
      u64 dk[8];
#pragma unroll
      for (int t = 0; t < 8; ++t) dk[t] = __shfl(d_l, s * 8 + t, 64);
#pragma unroll
      for (int t = 0; t < 8; ++t) {
        int k = s * 8 + t;
        u64 bit = (sup_word >> k) & 1ULL;
        keep_word |= (bit ^ 1ULL) << k;
        u64 mk = dk[t] & ~((2ULL << k) - 1ULL);
        sup_word |= mk & (bit - 1ULL);
      }
    }
    u64 acc = 0;
#pragma unroll
    for (int t = 0; t < 64; ++t)
      acc |= ((keep_word >> t) & 1ULL) ? rowv[t] : 0ULL;
    r |= acc;
    if (lane == 0) kwLDS[g] = keep_word;
    nk += __popcll(keep_word);
    if (nk >= POST) break;
  }
  __syncthreads();
  u64 kw = kwLDS[lane];
  int cnt = __popcll(kw);
  int pfx = cnt;
#pragma unroll
  for (int d = 1; d < 64; d <<= 1) {
    int up = __shfl_up(pfx, d, 64);
    if (lane >= d) pfx += up;
  }
  int total = __shfl(pfx, 63, 64);
  int pos = pfx - cnt;
  while (kw) {
    int t = __ffsll((long long)kw) - 1;
    kw &= kw - 1;
    if (pos < POST) keepIdx[b * POST + pos] = lane * 64 + t;
    ++pos;
  }
  if (lane == 0) keepCount[b] = total < POST ? total : POST;
}

// Write all 512 slots per batch: kept -> data, empty -> 0 (label 1).
__global__ void output_kernel(const int* __restrict__ keepIdx, const int* __restrict__ keepCount,
                              const float* __restrict__ topBox, const float* __restrict__ topS,
                              const int* __restrict__ topL, float* __restrict__ out) {
  int g = blockIdx.x * blockDim.x + threadIdx.x;
  if (g >= BB * POST) return;
  int b = g >> 9, s = g & (POST - 1);
  float* outR = out;
  float* outS = out + BB * POST * 7;
  float* outL = outS + BB * POST;
  int cnt = keepCount[b];
  if (s < cnt) {
    int i = keepIdx[g];
    const float* tb = topBox + ((size_t)(b << 12) + i) * 7;
#pragma unroll
    for (int c = 0; c < 7; ++c) outR[(size_t)g * 7 + c] = tb[c];
    outS[g] = topS[(b << 12) + i];
    outL[g] = (float)(topL[(b << 12) + i] + 1);
  } else {
#pragma unroll
    for (int c = 0; c < 7; ++c) outR[(size_t)g * 7 + c] = 0.0f;
    outS[g] = 0.0f;
    outL[g] = 1.0f;
  }
}

extern "C" void kernel_launch(void* const* d_in, const int* in_sizes, int n_in,
                              void* d_out, int out_size, void* d_ws, size_t ws_size,
                              hipStream_t stream) {
  const float* boxes = (const float*)d_in[0];   // (4,32768,7)
  const float* cls   = (const float*)d_in[1];   // (4,32768,3)
  float* out = (float*)d_out;

  // ---- workspace carve-up (~11 MB) ----
  char* p = (char*)d_ws;
  auto take = [&](size_t bytes) { char* r = p; p += (bytes + 255) & ~(size_t)255; return (void*)r; };
  u64*   keys    = (u64*)  take((size_t)BB * NN * 8);
  int*   labels  = (int*)  take((size_t)BB * NN * 4);
  u32*   hist    = (u32*)  take((size_t)BB * 2048 * 4);
  u32*   selinfo = (u32*)  take((size_t)BB * 2 * 4);
  u32*   cnt_hi  = (u32*)  take((size_t)BB * 4);
  u32*   cnt_mid = (u32*)  take((size_t)BB * 4);
  u64*   sel     = (u64*)  take((size_t)BB * PRE * 8);
  u64*   mid     = (u64*)  take((size_t)BB * MIDCAP * 8);
  float* topBox  = (float*)take((size_t)BB * PRE * 7 * 4);
  float4* Pb     = (float4*)take((size_t)BB * PRE * 16);
  float* AR      = (float*)take((size_t)BB * PRE * 4);
  float* topS    = (float*)take((size_t)BB * PRE * 4);
  int*   topL    = (int*)  take((size_t)BB * PRE * 4);
  u64*   maskBuf = (u64*)  take((size_t)BB * PRE * 64 * 8);
  u64*   diagBuf = (u64*)  take((size_t)BB * PRE * 8);
  int*   keepIdx = (int*)  take((size_t)BB * POST * 4);
  int*   keepCnt = (int*)  take((size_t)BB * 4);

  zero_kernel<<<32, 256, 0, stream>>>(hist, cnt_hi, cnt_mid);
  score_hist_kernel<<<BB * NN / 256, 256, 0, stream>>>(cls, labels, keys, hist);
  select_kernel<<<BB, 256, 0, stream>>>(hist, selinfo);
  compact_kernel<<<BB * NN / 2048, 256, 0, stream>>>(keys, selinfo, sel, mid, cnt_hi, cnt_mid);
  midsel_kernel<<<BB, 64, 0, stream>>>(mid, selinfo, cnt_mid, sel);
  sort4k_kernel<<<BB, 512, 0, stream>>>(sel);
  gather_kernel<<<(BB * PRE + 255) / 256, 256, 0, stream>>>(sel, boxes, labels,
                                                            topBox, Pb, AR, topS, topL);
  mask_kernel<<<dim3(64, 64, BB), 64, 0, stream>>>(Pb, AR, maskBuf, diagBuf);
  scan_kernel<<<BB, 64, 0, stream>>>(maskBuf, diagBuf, keepIdx, keepCnt);
  output_kernel<<<(BB * POST + 255) / 256, 256, 0, stream>>>(keepIdx, keepCnt, topBox, topS, topL, out);
}

// Round 7
// 128.980 us; speedup vs baseline: 3.1256x; 1.7213x over previous
//
#include <hip/hip_runtime.h>
#include <stdint.h>

#define BB 4
#define NN 32768
#define PRE 4096
#define POST 512
#define NMS_TH 0.7f
#define MIDCAP 8192

typedef unsigned long long u64;
typedef unsigned int u32;

__device__ __forceinline__ u32 orderable(float f) {
  u32 u = __float_as_uint(f);
  return (u & 0x80000000u) ? ~u : (u | 0x80000000u);
}
__device__ __forceinline__ float unorderable(u32 o) {
  u32 u = (o & 0x80000000u) ? (o & 0x7fffffffu) : ~o;
  return __uint_as_float(u);
}
// Monotone fixed-point bucket: uniform in score space (scores in [0,1)).
__device__ __forceinline__ u32 bucket_of(float s) {
  u32 v = (u32)(s * 2147483648.0f);
  u32 bk = v >> 20;
  return bk > 2047u ? 2047u : bk;
}

// Zero the histogram + mid counter (ws is not re-poisoned between replays).
__global__ void zero_kernel(u32* __restrict__ hist, u32* __restrict__ cnt_mid) {
  int t = blockIdx.x * 256 + threadIdx.x;
  if (t < BB * 2048) hist[t] = 0;
  if (t < BB) cnt_mid[t] = 0;
}

// score = max over 3 classes, label = first argmax, key = orderable(score)||~idx.
// Histogram fixed-point bucket per batch.
__global__ __launch_bounds__(256) void score_hist_kernel(const float* __restrict__ cls,
                                                         int* __restrict__ labels,
                                                         u64* __restrict__ keys,
                                                         u32* __restrict__ hist) {
  __shared__ u32 lh[2048];
  for (int t = threadIdx.x; t < 2048; t += 256) lh[t] = 0;
  __syncthreads();
  int g = blockIdx.x * 256 + threadIdx.x;           // BB*NN is an exact multiple of 256
  const float* c = cls + (size_t)g * 3;
  float s = c[0]; int l = 0;
  float c1 = c[1], c2 = c[2];
  if (c1 > s) { s = c1; l = 1; }
  if (c2 > s) { s = c2; l = 2; }
  int n = g & (NN - 1);
  keys[g] = ((u64)orderable(s) << 32) | (u32)(~(u32)n);
  labels[g] = l;
  atomicAdd(&lh[bucket_of(s)], 1u);
  __syncthreads();
  int b = blockIdx.x >> 7;                           // 128 blocks per batch
  for (int t = threadIdx.x; t < 2048; t += 256) {
    u32 v = lh[t];
    if (v) atomicAdd(&hist[b * 2048 + t], v);
  }
}

// Per batch: suffix-scan the histogram; find threshold bucket T with
// count(>T) < PRE <= count(>=T); persist sfx and init per-bucket cursors
// (cursor[t] = start of bucket t's segment in the final descending order).
__global__ __launch_bounds__(256) void select_kernel(const u32* __restrict__ hist,
                                                     u32* __restrict__ selinfo,
                                                     u32* __restrict__ sfxBuf,
                                                     u32* __restrict__ cursor) {
  __shared__ u32 sfx[2048];
  int b = blockIdx.x;
  for (int t = threadIdx.x; t < 2048; t += 256) sfx[t] = hist[b * 2048 + t];
  __syncthreads();
  for (int d = 1; d < 2048; d <<= 1) {
    u32 v[8];
#pragma unroll
    for (int i = 0; i < 8; ++i) {
      int t = threadIdx.x + i * 256;
      v[i] = (t + d < 2048) ? sfx[t + d] : 0;
    }
    __syncthreads();
#pragma unroll
    for (int i = 0; i < 8; ++i) sfx[threadIdx.x + i * 256] += v[i];
    __syncthreads();
  }
  for (int t = threadIdx.x; t < 2048; t += 256) {
    u32 above = (t + 1 < 2048) ? sfx[t + 1] : 0;
    sfxBuf[b * 2048 + t] = sfx[t];
    cursor[b * 2048 + t] = above;                       // segment base
    if (above < PRE && sfx[t] >= PRE) { selinfo[b * 2] = (u32)t; selinfo[b * 2 + 1] = above; }
  }
}

// Compact: hi keys scatter directly into their bucket's segment of sel via
// per-bucket cursors (2048 addresses/batch -> low contention); mid keys go to
// the tie-break buffer. Within-segment order arbitrary; bsort fixes it.
__global__ __launch_bounds__(256) void compact_kernel(const u64* __restrict__ keys,
                                                      const u32* __restrict__ selinfo,
                                                      u32* __restrict__ cursor,
                                                      u64* __restrict__ sel, u64* __restrict__ mid,
                                                      u32* __restrict__ cnt_mid) {
  int g = blockIdx.x * 256 + threadIdx.x;
  int b = g >> 15;
  u64 key = keys[g];
  u32 bk = bucket_of(unorderable((u32)(key >> 32)));
  u32 T = selinfo[b * 2];
  if (bk > T) {
    u32 p = atomicAdd(&cursor[b * 2048 + bk], 1u);
    sel[((size_t)b << 12) + p] = key;
  } else if (bk == T) {
    u32 p = atomicAdd(&cnt_mid[b], 1u);
    if (p < MIDCAP) mid[(size_t)b * MIDCAP + p] = key;   // ~45 expected with this data
  }
}

// One wave per (batch, bucket). Buckets > T: in-register 64-lane bitonic sort
// of the segment (descending; zero-padding sinks). Bucket == T: pick the top
// (PRE-C1) mid keys by repeated wave argmax (fused midsel). Buckets < T: no-op.
__global__ __launch_bounds__(64) void bsort_kernel(u64* __restrict__ sel, u64* __restrict__ mid,
                                                   const u32* __restrict__ sfxBuf,
                                                   const u32* __restrict__ selinfo,
                                                   const u32* __restrict__ cnt_mid) {
  int t = blockIdx.x & 2047;
  int b = blockIdx.x >> 11;
  int lane = threadIdx.x;
  u32 T = selinfo[b * 2];
  u64* selB = sel + ((size_t)b << 12);
  if ((u32)t == T) {
    u32 C1 = selinfo[b * 2 + 1];
    int need = PRE - (int)C1;
    int M = (int)cnt_mid[b]; if (M > MIDCAP) M = MIDCAP;
    u64* midB = mid + (size_t)b * MIDCAP;
    for (int r = 0; r < need; ++r) {
      u64 best = 0; int bi = -1;
      for (int q = lane; q < M; q += 64) {
        u64 v = midB[q];
        if (v > best) { best = v; bi = q; }
      }
#pragma unroll
      for (int d = 32; d > 0; d >>= 1) {
        u64 ob = __shfl_xor(best, d, 64);
        int oi = __shfl_xor(bi, d, 64);
        if (ob > best) { best = ob; bi = oi; }
      }
      if (lane == 0) selB[C1 + r] = best;
      if (bi >= 0 && lane == (bi & 63)) midB[bi] = 0;    // remove chosen
    }
    return;
  }
  if ((u32)t < T) return;
  u32 start = (t < 2047) ? sfxBuf[b * 2048 + t + 1] : 0u;
  u32 end = sfxBuf[b * 2048 + t];
  int n = (int)(end - start);
  if (n <= 1) return;
  if (n <= 64) {
    u64 v = (lane < n) ? selB[start + lane] : 0ULL;      // real keys have MSB set -> pad sinks
#pragma unroll
    for (int k = 2; k <= 64; k <<= 1) {
#pragma unroll
      for (int j = k >> 1; j > 0; j >>= 1) {
        u64 o = __shfl_xor(v, j, 64);
        bool up = ((lane & k) == 0);                     // k=64 -> desc everywhere
        bool first = ((lane & j) == 0);
        u64 mx = v > o ? v : o, mn = v > o ? o : v;
        v = (first == up) ? mx : mn;
      }
    }
    if (lane < n) selB[start + lane] = v;
  } else {
    // robustness fallback (never hit on bench data): selection sort by wave argmax
    for (int r = 0; r < n - 1; ++r) {
      u64 best = 0; int bi = -1;
      for (int q = r + lane; q < n; q += 64) {
        u64 v = selB[start + q];
        if (v > best) { best = v; bi = q; }
      }
#pragma unroll
      for (int d = 32; d > 0; d >>= 1) {
        u64 ob = __shfl_xor(best, d, 64);
        int oi = __shfl_xor(bi, d, 64);
        if (ob > best) { best = ob; bi = oi; }
      }
      if (lane == 0) {
        u64 tmp = selB[start + r];
        selB[start + r] = best;
        selB[start + bi] = tmp;
      }
    }
  }
}

// Gather top-4096 boxes; pack bounds as float4 + area; recover score from key bits.
__global__ void gather_kernel(const u64* __restrict__ keys, const float* __restrict__ boxes,
                              const int* __restrict__ labels,
                              float* __restrict__ topBox, float4* __restrict__ P,
                              float* __restrict__ AR,
                              float* __restrict__ topS, int* __restrict__ topL) {
  int g = blockIdx.x * blockDim.x + threadIdx.x;
  if (g >= BB * PRE) return;
  int b = g >> 12;
  u64 key = keys[g];
  u32 n = ~(u32)key;
  size_t src = (size_t)b * NN + n;
  const float* bx = boxes + src * 7;
  float x = bx[0], y = bx[1], dx = bx[3], dy = bx[4];
  float* tb = topBox + (size_t)g * 7;
#pragma unroll
  for (int c = 0; c < 7; ++c) tb[c] = bx[c];
  float4 p;
  p.x = x - 0.5f * dx; p.z = x + 0.5f * dx;   // 0.5*dx exact -> contraction-safe
  p.y = y - 0.5f * dy; p.w = y + 0.5f * dy;
  P[g] = p;
  AR[g] = dx * dy;
  topS[g] = unorderable((u32)(key >> 32));
  topL[g] = labels[src];
}

// Ballot-form suppression mask. One wave per 64x64 tile; lane = column.
// Row k's values broadcast by shfl; word = __ballot(sup). Divide eliminated by
// inter > 0.7*denom with a conservative marginal band; wave falls back to the
// exact IEEE divide if any lane is within the band (bitwise == numpy).
__global__ __launch_bounds__(64) void mask_kernel(const float4* __restrict__ P,
                                                  const float* __restrict__ AR,
                                                  u64* __restrict__ mask,
                                                  u64* __restrict__ diag) {
  int w = blockIdx.x;         // column word 0..63
  int rb = blockIdx.y;        // row block 0..63
  int b = blockIdx.z;
  if (w < rb) return;         // strictly-below-diagonal tile: dead for the scan
  int lane = threadIdx.x;
  int base = b << 12;
  float4 cp = P[base + (w << 6) + lane];    // this lane's column box
  float car = AR[base + (w << 6) + lane];
  float4 rp = P[base + (rb << 6) + lane];   // this lane's row box (shfl source)
  float rar = AR[base + (rb << 6) + lane];
  u64 myword = 0;
#pragma unroll
  for (int k = 0; k < 64; ++k) {
    float bx1 = __shfl(rp.x, k, 64);
    float by1 = __shfl(rp.y, k, 64);
    float bx2 = __shfl(rp.z, k, 64);
    float by2 = __shfl(rp.w, k, 64);
    float bar = __shfl(rar, k, 64);
    float ix = fminf(bx2, cp.z) - fmaxf(bx1, cp.x); ix = fmaxf(0.0f, ix);
    float iy = fminf(by2, cp.w) - fmaxf(by1, cp.y); iy = fmaxf(0.0f, iy);
    float inter = ix * iy;
    float denom = ((bar + car) - inter) + 1e-6f;     // same op order as reference
    float t = 0.7f * denom;                          // denom >= 1 here, t > 0
    bool sup;
    bool marginal = fabsf(inter - t) <= 2e-5f * t;   // band >> max rounding skew (~4e-7)
    if (__any(marginal)) sup = (inter / denom) > NMS_TH;  // exact IEEE path
    else sup = inter > t;
    u64 word = __ballot(sup);
    if (lane == k) myword = word;
  }
  int row = (rb << 6) + lane;
  mask[(size_t)(base + row) * 64 + w] = myword;
  if (w == rb) diag[base + row] = myword;
}

// Greedy scan, group-of-64 formulation. One wave per batch.
__global__ __launch_bounds__(64) void scan_kernel(const u64* __restrict__ mask,
                                                  const u64* __restrict__ diag,
                                                  int* __restrict__ keepIdx,
                                                  int* __restrict__ keepCount) {
  __shared__ u64 kwLDS[64];
  int b = blockIdx.x;
  int lane = threadIdx.x;
  const u64* m = mask + (size_t)b * PRE * 64;
  const u64* dg = diag + (size_t)b * PRE;
  kwLDS[lane] = 0;
  __syncthreads();
  u64 r = 0;
  int nk = 0;
  for (int g = 0; g < PRE / 64; ++g) {
    u64 d_l = dg[g * 64 + lane];
    u64 rowv[64];
#pragma unroll
    for (int t = 0; t < 64; ++t) rowv[t] = m[((size_t)(g * 64 + t)) * 64 + lane];
    u64 sup_word = __shfl(r, g, 64);
    u64 keep_word = 0;
#pragma unroll
    for (int s = 0; s < 8; ++s) {
      u64 dk[8];
#pragma unroll
      for (int t = 0; t < 8; ++t) dk[t] = __shfl(d_l, s * 8 + t, 64);
#pragma unroll
      for (int t = 0; t < 8; ++t) {
        int k = s * 8 + t;
        u64 bit = (sup_word >> k) & 1ULL;
        keep_word |= (bit ^ 1ULL) << k;
        u64 mk = dk[t] & ~((2ULL << k) - 1ULL);
        sup_word |= mk & (bit - 1ULL);
      }
    }
    u64 acc = 0;
#pragma unroll
    for (int t = 0; t < 64; ++t)
      acc |= ((keep_word >> t) & 1ULL) ? rowv[t] : 0ULL;
    r |= acc;
    if (lane == 0) kwLDS[g] = keep_word;
    nk += __popcll(keep_word);
    if (nk >= POST) break;
  }
  __syncthreads();
  u64 kw = kwLDS[lane];
  int cnt = __popcll(kw);
  int pfx = cnt;
#pragma unroll
  for (int d = 1; d < 64; d <<= 1) {
    int up = __shfl_up(pfx, d, 64);
    if (lane >= d) pfx += up;
  }
  int total = __shfl(pfx, 63, 64);
  int pos = pfx - cnt;
  while (kw) {
    int t = __ffsll((long long)kw) - 1;
    kw &= kw - 1;
    if (pos < POST) keepIdx[b * POST + pos] = lane * 64 + t;
    ++pos;
  }
  if (lane == 0) keepCount[b] = total < POST ? total : POST;
}

// Write all 512 slots per batch: kept -> data, empty -> 0 (label 1).
__global__ void output_kernel(const int* __restrict__ keepIdx, const int* __restrict__ keepCount,
                              const float* __restrict__ topBox, const float* __restrict__ topS,
                              const int* __restrict__ topL, float* __restrict__ out) {
  int g = blockIdx.x * blockDim.x + threadIdx.x;
  if (g >= BB * POST) return;
  int b = g >> 9, s = g & (POST - 1);
  float* outR = out;
  float* outS = out + BB * POST * 7;
  float* outL = outS + BB * POST;
  int cnt = keepCount[b];
  if (s < cnt) {
    int i = keepIdx[g];
    const float* tb = topBox + ((size_t)(b << 12) + i) * 7;
#pragma unroll
    for (int c = 0; c < 7; ++c) outR[(size_t)g * 7 + c] = tb[c];
    outS[g] = topS[(b << 12) + i];
    outL[g] = (float)(topL[(b << 12) + i] + 1);
  } else {
#pragma unroll
    for (int c = 0; c < 7; ++c) outR[(size_t)g * 7 + c] = 0.0f;
    outS[g] = 0.0f;
    outL[g] = 1.0f;
  }
}

extern "C" void kernel_launch(void* const* d_in, const int* in_sizes, int n_in,
                              void* d_out, int out_size, void* d_ws, size_t ws_size,
                              hipStream_t stream) {
  const float* boxes = (const float*)d_in[0];   // (4,32768,7)
  const float* cls   = (const float*)d_in[1];   // (4,32768,3)
  float* out = (float*)d_out;

  // ---- workspace carve-up (~11 MB) ----
  char* p = (char*)d_ws;
  auto take = [&](size_t bytes) { char* r = p; p += (bytes + 255) & ~(size_t)255; return (void*)r; };
  u64*   keys    = (u64*)  take((size_t)BB * NN * 8);
  int*   labels  = (int*)  take((size_t)BB * NN * 4);
  u32*   hist    = (u32*)  take((size_t)BB * 2048 * 4);
  u32*   selinfo = (u32*)  take((size_t)BB * 2 * 4);
  u32*   sfxBuf  = (u32*)  take((size_t)BB * 2048 * 4);
  u32*   cursor  = (u32*)  take((size_t)BB * 2048 * 4);
  u32*   cnt_mid = (u32*)  take((size_t)BB * 4);
  u64*   sel     = (u64*)  take((size_t)BB * PRE * 8);
  u64*   mid     = (u64*)  take((size_t)BB * MIDCAP * 8);
  float* topBox  = (float*)take((size_t)BB * PRE * 7 * 4);
  float4* Pb     = (float4*)take((size_t)BB * PRE * 16);
  float* AR      = (float*)take((size_t)BB * PRE * 4);
  float* topS    = (float*)take((size_t)BB * PRE * 4);
  int*   topL    = (int*)  take((size_t)BB * PRE * 4);
  u64*   maskBuf = (u64*)  take((size_t)BB * PRE * 64 * 8);
  u64*   diagBuf = (u64*)  take((size_t)BB * PRE * 8);
  int*   keepIdx = (int*)  take((size_t)BB * POST * 4);
  int*   keepCnt = (int*)  take((size_t)BB * 4);

  zero_kernel<<<32, 256, 0, stream>>>(hist, cnt_mid);
  score_hist_kernel<<<BB * NN / 256, 256, 0, stream>>>(cls, labels, keys, hist);
  select_kernel<<<BB, 256, 0, stream>>>(hist, selinfo, sfxBuf, cursor);
  compact_kernel<<<BB * NN / 256, 256, 0, stream>>>(keys, selinfo, cursor, sel, mid, cnt_mid);
  bsort_kernel<<<BB * 2048, 64, 0, stream>>>(sel, mid, sfxBuf, selinfo, cnt_mid);
  gather_kernel<<<(BB * PRE + 255) / 256, 256, 0, stream>>>(sel, boxes, labels,
                                                            topBox, Pb, AR, topS, topL);
  mask_kernel<<<dim3(64, 64, BB), 64, 0, stream>>>(Pb, AR, maskBuf, diagBuf);
  scan_kernel<<<BB, 64, 0, stream>>>(maskBuf, diagBuf, keepIdx, keepCnt);
  output_kernel<<<(BB * POST + 255) / 256, 256, 0, stream>>>(keepIdx, keepCnt, topBox, topS, topL, out);
}

// Round 8
// 114.472 us; speedup vs baseline: 3.5217x; 1.1267x over previous
//
#include <hip/hip_runtime.h>
#include <stdint.h>

#define BB 4
#define NN 32768
#define PRE 4096
#define POST 512
#define NMS_TH 0.7f
#define MIDCAP 8192

typedef unsigned long long u64;
typedef unsigned int u32;

__device__ __forceinline__ u32 orderable(float f) {
  u32 u = __float_as_uint(f);
  return (u & 0x80000000u) ? ~u : (u | 0x80000000u);
}
__device__ __forceinline__ float unorderable(u32 o) {
  u32 u = (o & 0x80000000u) ? (o & 0x7fffffffu) : ~o;
  return __uint_as_float(u);
}
// Monotone fixed-point bucket: uniform in score space (scores in [0,1)).
__device__ __forceinline__ u32 bucket_of(float s) {
  u32 v = (u32)(s * 2147483648.0f);
  u32 bk = v >> 20;
  return bk > 2047u ? 2047u : bk;
}

// Zero the histogram + mid counter (ws is not re-poisoned between replays).
__global__ void zero_kernel(u32* __restrict__ hist, u32* __restrict__ cnt_mid) {
  int t = blockIdx.x * 256 + threadIdx.x;
  if (t < BB * 2048) hist[t] = 0;
  if (t < BB) cnt_mid[t] = 0;
}

// score = max over 3 classes, label = first argmax, key = orderable(score)||~idx.
// Histogram fixed-point bucket per batch.
__global__ __launch_bounds__(256) void score_hist_kernel(const float* __restrict__ cls,
                                                         int* __restrict__ labels,
                                                         u64* __restrict__ keys,
                                                         u32* __restrict__ hist) {
  __shared__ u32 lh[2048];
  for (int t = threadIdx.x; t < 2048; t += 256) lh[t] = 0;
  __syncthreads();
  int g = blockIdx.x * 256 + threadIdx.x;           // BB*NN is an exact multiple of 256
  const float* c = cls + (size_t)g * 3;
  float s = c[0]; int l = 0;
  float c1 = c[1], c2 = c[2];
  if (c1 > s) { s = c1; l = 1; }
  if (c2 > s) { s = c2; l = 2; }
  int n = g & (NN - 1);
  keys[g] = ((u64)orderable(s) << 32) | (u32)(~(u32)n);
  labels[g] = l;
  atomicAdd(&lh[bucket_of(s)], 1u);
  __syncthreads();
  int b = blockIdx.x >> 7;                           // 128 blocks per batch
  for (int t = threadIdx.x; t < 2048; t += 256) {
    u32 v = lh[t];
    if (v) atomicAdd(&hist[b * 2048 + t], v);
  }
}

// Per batch: suffix-scan the histogram; find threshold bucket T with
// count(>T) < PRE <= count(>=T); persist sfx and init per-bucket cursors
// (cursor[t] = start of bucket t's segment in the final descending order).
__global__ __launch_bounds__(256) void select_kernel(const u32* __restrict__ hist,
                                                     u32* __restrict__ selinfo,
                                                     u32* __restrict__ sfxBuf,
                                                     u32* __restrict__ cursor) {
  __shared__ u32 sfx[2048];
  int b = blockIdx.x;
  for (int t = threadIdx.x; t < 2048; t += 256) sfx[t] = hist[b * 2048 + t];
  __syncthreads();
  for (int d = 1; d < 2048; d <<= 1) {
    u32 v[8];
#pragma unroll
    for (int i = 0; i < 8; ++i) {
      int t = threadIdx.x + i * 256;
      v[i] = (t + d < 2048) ? sfx[t + d] : 0;
    }
    __syncthreads();
#pragma unroll
    for (int i = 0; i < 8; ++i) sfx[threadIdx.x + i * 256] += v[i];
    __syncthreads();
  }
  for (int t = threadIdx.x; t < 2048; t += 256) {
    u32 above = (t + 1 < 2048) ? sfx[t + 1] : 0;
    sfxBuf[b * 2048 + t] = sfx[t];
    cursor[b * 2048 + t] = above;                       // segment base
    if (above < PRE && sfx[t] >= PRE) { selinfo[b * 2] = (u32)t; selinfo[b * 2 + 1] = above; }
  }
}

// Compact: hi keys scatter directly into their bucket's segment of sel via
// per-bucket cursors (2048 addresses/batch -> low contention); mid keys go to
// the tie-break buffer. Within-segment order arbitrary; bsort fixes it.
__global__ __launch_bounds__(256) void compact_kernel(const u64* __restrict__ keys,
                                                      const u32* __restrict__ selinfo,
                                                      u32* __restrict__ cursor,
                                                      u64* __restrict__ sel, u64* __restrict__ mid,
                                                      u32* __restrict__ cnt_mid) {
  int g = blockIdx.x * 256 + threadIdx.x;
  int b = g >> 15;
  u64 key = keys[g];
  u32 bk = bucket_of(unorderable((u32)(key >> 32)));
  u32 T = selinfo[b * 2];
  if (bk > T) {
    u32 p = atomicAdd(&cursor[b * 2048 + bk], 1u);
    sel[((size_t)b << 12) + p] = key;
  } else if (bk == T) {
    u32 p = atomicAdd(&cnt_mid[b], 1u);
    if (p < MIDCAP) mid[(size_t)b * MIDCAP + p] = key;   // ~45 expected with this data
  }
}

// One wave per (batch, bucket). Buckets > T: in-register 64-lane bitonic sort
// of the segment (descending; zero-padding sinks). Bucket == T: pick the top
// (PRE-C1) mid keys by repeated wave argmax (fused midsel). Buckets < T: no-op.
__global__ __launch_bounds__(64) void bsort_kernel(u64* __restrict__ sel, u64* __restrict__ mid,
                                                   const u32* __restrict__ sfxBuf,
                                                   const u32* __restrict__ selinfo,
                                                   const u32* __restrict__ cnt_mid) {
  int t = blockIdx.x & 2047;
  int b = blockIdx.x >> 11;
  int lane = threadIdx.x;
  u32 T = selinfo[b * 2];
  u64* selB = sel + ((size_t)b << 12);
  if ((u32)t == T) {
    u32 C1 = selinfo[b * 2 + 1];
    int need = PRE - (int)C1;
    int M = (int)cnt_mid[b]; if (M > MIDCAP) M = MIDCAP;
    u64* midB = mid + (size_t)b * MIDCAP;
    for (int r = 0; r < need; ++r) {
      u64 best = 0; int bi = -1;
      for (int q = lane; q < M; q += 64) {
        u64 v = midB[q];
        if (v > best) { best = v; bi = q; }
      }
#pragma unroll
      for (int d = 32; d > 0; d >>= 1) {
        u64 ob = __shfl_xor(best, d, 64);
        int oi = __shfl_xor(bi, d, 64);
        if (ob > best) { best = ob; bi = oi; }
      }
      if (lane == 0) selB[C1 + r] = best;
      if (bi >= 0 && lane == (bi & 63)) midB[bi] = 0;    // remove chosen
    }
    return;
  }
  if ((u32)t < T) return;
  u32 start = (t < 2047) ? sfxBuf[b * 2048 + t + 1] : 0u;
  u32 end = sfxBuf[b * 2048 + t];
  int n = (int)(end - start);
  if (n <= 1) return;
  if (n <= 64) {
    u64 v = (lane < n) ? selB[start + lane] : 0ULL;      // real keys have MSB set -> pad sinks
#pragma unroll
    for (int k = 2; k <= 64; k <<= 1) {
#pragma unroll
      for (int j = k >> 1; j > 0; j >>= 1) {
        u64 o = __shfl_xor(v, j, 64);
        bool up = ((lane & k) == 0);                     // k=64 -> desc everywhere
        bool first = ((lane & j) == 0);
        u64 mx = v > o ? v : o, mn = v > o ? o : v;
        v = (first == up) ? mx : mn;
      }
    }
    if (lane < n) selB[start + lane] = v;
  } else {
    // robustness fallback (never hit on bench data): selection sort by wave argmax
    for (int r = 0; r < n - 1; ++r) {
      u64 best = 0; int bi = -1;
      for (int q = r + lane; q < n; q += 64) {
        u64 v = selB[start + q];
        if (v > best) { best = v; bi = q; }
      }
#pragma unroll
      for (int d = 32; d > 0; d >>= 1) {
        u64 ob = __shfl_xor(best, d, 64);
        int oi = __shfl_xor(bi, d, 64);
        if (ob > best) { best = ob; bi = oi; }
      }
      if (lane == 0) {
        u64 tmp = selB[start + r];
        selB[start + r] = best;
        selB[start + bi] = tmp;
      }
    }
  }
}

// Gather top-4096 boxes; pack bounds as float4 + area; recover score from key bits.
__global__ void gather_kernel(const u64* __restrict__ keys, const float* __restrict__ boxes,
                              const int* __restrict__ labels,
                              float* __restrict__ topBox, float4* __restrict__ P,
                              float* __restrict__ AR,
                              float* __restrict__ topS, int* __restrict__ topL) {
  int g = blockIdx.x * blockDim.x + threadIdx.x;
  if (g >= BB * PRE) return;
  int b = g >> 12;
  u64 key = keys[g];
  u32 n = ~(u32)key;
  size_t src = (size_t)b * NN + n;
  const float* bx = boxes + src * 7;
  float x = bx[0], y = bx[1], dx = bx[3], dy = bx[4];
  float* tb = topBox + (size_t)g * 7;
#pragma unroll
  for (int c = 0; c < 7; ++c) tb[c] = bx[c];
  float4 p;
  p.x = x - 0.5f * dx; p.z = x + 0.5f * dx;   // 0.5*dx exact -> contraction-safe
  p.y = y - 0.5f * dy; p.w = y + 0.5f * dy;
  P[g] = p;
  AR[g] = dx * dy;
  topS[g] = unorderable((u32)(key >> 32));
  topL[g] = labels[src];
}

// Suppression mask, lane=row form. One wave per upper-tri 64x64 tile (w >= rb).
// Lane owns row rb*64+lane; column k's box broadcast via shfl; mask word built
// in-register (no ballot). Word-major layout maskT[b][w][row]: the wave's 64
// lanes write 64 consecutive u64 -> one coalesced 512B store per tile.
// Divide eliminated by inter > 0.7*denom with conservative marginal band;
// wave falls back to exact IEEE divide if any lane is in the band.
__global__ __launch_bounds__(256) void mask_kernel(const float4* __restrict__ P,
                                                   const float* __restrict__ AR,
                                                   u64* __restrict__ maskT,
                                                   u64* __restrict__ diag) {
  int b = blockIdx.y;
  int ti = blockIdx.x * 4 + (threadIdx.x >> 6);   // 2080 upper-tri tiles per batch
  int lane = threadIdx.x & 63;
  // triangular decode: ti -> (rb, w), w >= rb (any bijection works)
  int u = 2079 - ti;
  int m = (int)((sqrtf(8.0f * (float)u + 1.0f) - 1.0f) * 0.5f);
  while ((m + 1) * (m + 2) / 2 <= u) ++m;         // wave-uniform fixup
  while (m * (m + 1) / 2 > u) --m;
  int rb = 63 - m;
  int w = rb + (u - m * (m + 1) / 2);
  int base = b << 12;
  int row = (rb << 6) + lane;
  float4 rp = P[base + row];               float rar = AR[base + row];
  float4 cp = P[base + (w << 6) + lane];   float car = AR[base + (w << 6) + lane];
  u64 bits = 0;
#pragma unroll
  for (int k = 0; k < 64; ++k) {
    float cx1 = __shfl(cp.x, k, 64);
    float cy1 = __shfl(cp.y, k, 64);
    float cx2 = __shfl(cp.z, k, 64);
    float cy2 = __shfl(cp.w, k, 64);
    float ca  = __shfl(car, k, 64);
    float ix = fminf(rp.z, cx2) - fmaxf(rp.x, cx1); ix = fmaxf(0.0f, ix);
    float iy = fminf(rp.w, cy2) - fmaxf(rp.y, cy1); iy = fmaxf(0.0f, iy);
    float inter = ix * iy;
    float denom = ((rar + ca) - inter) + 1e-6f;      // same op order as reference
    float t = 0.7f * denom;                          // denom >= 1 here, t > 0
    bool sup;
    bool marginal = fabsf(inter - t) <= 2e-5f * t;   // band >> max rounding skew (~4e-7)
    if (__any(marginal)) sup = (inter / denom) > NMS_TH;  // exact IEEE path
    else sup = inter > t;
    bits |= ((u64)(sup ? 1u : 0u)) << k;
  }
  maskT[((size_t)(b * 64 + w)) * PRE + row] = bits;  // coalesced 512B per tile
  if (w == rb) diag[base + row] = bits;
}

// Greedy scan, group-of-64 formulation. One wave per batch.
// Word-major mask: lane's row words are contiguous per group (512B run),
// loaded as 16B ulonglong2.
__global__ __launch_bounds__(64) void scan_kernel(const u64* __restrict__ maskT,
                                                  const u64* __restrict__ diag,
                                                  int* __restrict__ keepIdx,
                                                  int* __restrict__ keepCount) {
  __shared__ u64 kwLDS[64];
  int b = blockIdx.x;
  int lane = threadIdx.x;
  const u64* m = maskT + (size_t)b * 64 * PRE;
  const u64* dg = diag + (size_t)b * PRE;
  kwLDS[lane] = 0;
  __syncthreads();
  u64 r = 0;
  int nk = 0;
  for (int g = 0; g < PRE / 64; ++g) {
    u64 d_l = dg[g * 64 + lane];
    const ulonglong2* mp = (const ulonglong2*)(m + (size_t)lane * PRE + (g << 6));
    ulonglong2 rv[32];
#pragma unroll
    for (int q = 0; q < 32; ++q) rv[q] = mp[q];
    u64 sup_word = __shfl(r, g, 64);
    u64 keep_word = 0;
#pragma unroll
    for (int s = 0; s < 8; ++s) {
      u64 dk[8];
#pragma unroll
      for (int t = 0; t < 8; ++t) dk[t] = __shfl(d_l, s * 8 + t, 64);
#pragma unroll
      for (int t = 0; t < 8; ++t) {
        int k = s * 8 + t;
        u64 bit = (sup_word >> k) & 1ULL;
        keep_word |= (bit ^ 1ULL) << k;
        u64 mk = dk[t] & ~((2ULL << k) - 1ULL);
        sup_word |= mk & (bit - 1ULL);
      }
    }
    u64 acc = 0;
#pragma unroll
    for (int q = 0; q < 32; ++q) {
      acc |= ((keep_word >> (2 * q)) & 1ULL) ? rv[q].x : 0ULL;
      acc |= ((keep_word >> (2 * q + 1)) & 1ULL) ? rv[q].y : 0ULL;
    }
    r |= acc;
    if (lane == 0) kwLDS[g] = keep_word;
    nk += __popcll(keep_word);
    if (nk >= POST) break;
  }
  __syncthreads();
  u64 kw = kwLDS[lane];
  int cnt = __popcll(kw);
  int pfx = cnt;
#pragma unroll
  for (int d = 1; d < 64; d <<= 1) {
    int up = __shfl_up(pfx, d, 64);
    if (lane >= d) pfx += up;
  }
  int total = __shfl(pfx, 63, 64);
  int pos = pfx - cnt;
  while (kw) {
    int t = __ffsll((long long)kw) - 1;
    kw &= kw - 1;
    if (pos < POST) keepIdx[b * POST + pos] = lane * 64 + t;
    ++pos;
  }
  if (lane == 0) keepCount[b] = total < POST ? total : POST;
}

// Write all 512 slots per batch: kept -> data, empty -> 0 (label 1).
__global__ void output_kernel(const int* __restrict__ keepIdx, const int* __restrict__ keepCount,
                              const float* __restrict__ topBox, const float* __restrict__ topS,
                              const int* __restrict__ topL, float* __restrict__ out) {
  int g = blockIdx.x * blockDim.x + threadIdx.x;
  if (g >= BB * POST) return;
  int b = g >> 9, s = g & (POST - 1);
  float* outR = out;
  float* outS = out + BB * POST * 7;
  float* outL = outS + BB * POST;
  int cnt = keepCount[b];
  if (s < cnt) {
    int i = keepIdx[g];
    const float* tb = topBox + ((size_t)(b << 12) + i) * 7;
#pragma unroll
    for (int c = 0; c < 7; ++c) outR[(size_t)g * 7 + c] = tb[c];
    outS[g] = topS[(b << 12) + i];
    outL[g] = (float)(topL[(b << 12) + i] + 1);
  } else {
#pragma unroll
    for (int c = 0; c < 7; ++c) outR[(size_t)g * 7 + c] = 0.0f;
    outS[g] = 0.0f;
    outL[g] = 1.0f;
  }
}

extern "C" void kernel_launch(void* const* d_in, const int* in_sizes, int n_in,
                              void* d_out, int out_size, void* d_ws, size_t ws_size,
                              hipStream_t stream) {
  const float* boxes = (const float*)d_in[0];   // (4,32768,7)
  const float* cls   = (const float*)d_in[1];   // (4,32768,3)
  float* out = (float*)d_out;

  // ---- workspace carve-up (~11 MB) ----
  char* p = (char*)d_ws;
  auto take = [&](size_t bytes) { char* r = p; p += (bytes + 255) & ~(size_t)255; return (void*)r; };
  u64*   keys    = (u64*)  take((size_t)BB * NN * 8);
  int*   labels  = (int*)  take((size_t)BB * NN * 4);
  u32*   hist    = (u32*)  take((size_t)BB * 2048 * 4);
  u32*   selinfo = (u32*)  take((size_t)BB * 2 * 4);
  u32*   sfxBuf  = (u32*)  take((size_t)BB * 2048 * 4);
  u32*   cursor  = (u32*)  take((size_t)BB * 2048 * 4);
  u32*   cnt_mid = (u32*)  take((size_t)BB * 4);
  u64*   sel     = (u64*)  take((size_t)BB * PRE * 8);
  u64*   mid     = (u64*)  take((size_t)BB * MIDCAP * 8);
  float* topBox  = (float*)take((size_t)BB * PRE * 7 * 4);
  float4* Pb     = (float4*)take((size_t)BB * PRE * 16);
  float* AR      = (float*)take((size_t)BB * PRE * 4);
  float* topS    = (float*)take((size_t)BB * PRE * 4);
  int*   topL    = (int*)  take((size_t)BB * PRE * 4);
  u64*   maskT   = (u64*)  take((size_t)BB * 64 * PRE * 8);
  u64*   diagBuf = (u64*)  take((size_t)BB * PRE * 8);
  int*   keepIdx = (int*)  take((size_t)BB * POST * 4);
  int*   keepCnt = (int*)  take((size_t)BB * 4);

  zero_kernel<<<32, 256, 0, stream>>>(hist, cnt_mid);
  score_hist_kernel<<<BB * NN / 256, 256, 0, stream>>>(cls, labels, keys, hist);
  select_kernel<<<BB, 256, 0, stream>>>(hist, selinfo, sfxBuf, cursor);
  compact_kernel<<<BB * NN / 256, 256, 0, stream>>>(keys, selinfo, cursor, sel, mid, cnt_mid);
  bsort_kernel<<<BB * 2048, 64, 0, stream>>>(sel, mid, sfxBuf, selinfo, cnt_mid);
  gather_kernel<<<(BB * PRE + 255) / 256, 256, 0, stream>>>(sel, boxes, labels,
                                                            topBox, Pb, AR, topS, topL);
  mask_kernel<<<dim3(520, BB), 256, 0, stream>>>(Pb, AR, maskT, diagBuf);
  scan_kernel<<<BB, 64, 0, stream>>>(maskT, diagBuf, keepIdx, keepCnt);
  output_kernel<<<(BB * POST + 255) / 256, 256, 0, stream>>>(keepIdx, keepCnt, topBox, topS, topL, out);
}

// Round 9
// 103.857 us; speedup vs baseline: 3.8816x; 1.1022x over previous
//
#include <hip/hip_runtime.h>
#include <stdint.h>

#define BB 4
#define NN 32768
#define PRE 4096
#define POST 512
#define NMS_TH 0.7f
#define MIDCAP 8192

typedef unsigned long long u64;
typedef unsigned int u32;

__device__ __forceinline__ u32 orderable(float f) {
  u32 u = __float_as_uint(f);
  return (u & 0x80000000u) ? ~u : (u | 0x80000000u);
}
__device__ __forceinline__ float unorderable(u32 o) {
  u32 u = (o & 0x80000000u) ? (o & 0x7fffffffu) : ~o;
  return __uint_as_float(u);
}
// Monotone fixed-point bucket: uniform in score space (scores in [0,1)).
__device__ __forceinline__ u32 bucket_of(float s) {
  u32 v = (u32)(s * 2147483648.0f);
  u32 bk = v >> 20;
  return bk > 2047u ? 2047u : bk;
}

// Zero the histogram + mid counter (ws is not re-poisoned between replays).
__global__ void zero_kernel(u32* __restrict__ hist, u32* __restrict__ cnt_mid) {
  int t = blockIdx.x * 256 + threadIdx.x;
  if (t < BB * 2048) hist[t] = 0;
  if (t < BB) cnt_mid[t] = 0;
}

// score = max over 3 classes, label = first argmax, key = orderable(score)||~idx.
// Histogram fixed-point bucket per batch.
__global__ __launch_bounds__(256) void score_hist_kernel(const float* __restrict__ cls,
                                                         int* __restrict__ labels,
                                                         u64* __restrict__ keys,
                                                         u32* __restrict__ hist) {
  __shared__ u32 lh[2048];
  for (int t = threadIdx.x; t < 2048; t += 256) lh[t] = 0;
  __syncthreads();
  int g = blockIdx.x * 256 + threadIdx.x;           // BB*NN is an exact multiple of 256
  const float* c = cls + (size_t)g * 3;
  float s = c[0]; int l = 0;
  float c1 = c[1], c2 = c[2];
  if (c1 > s) { s = c1; l = 1; }
  if (c2 > s) { s = c2; l = 2; }
  int n = g & (NN - 1);
  keys[g] = ((u64)orderable(s) << 32) | (u32)(~(u32)n);
  labels[g] = l;
  atomicAdd(&lh[bucket_of(s)], 1u);
  __syncthreads();
  int b = blockIdx.x >> 7;                           // 128 blocks per batch
  for (int t = threadIdx.x; t < 2048; t += 256) {
    u32 v = lh[t];
    if (v) atomicAdd(&hist[b * 2048 + t], v);
  }
}

// Per batch: suffix-scan the histogram; find threshold bucket T with
// count(>T) < PRE <= count(>=T); persist sfx and init per-bucket cursors
// (cursor[t] = start of bucket t's segment in the final descending order).
__global__ __launch_bounds__(256) void select_kernel(const u32* __restrict__ hist,
                                                     u32* __restrict__ selinfo,
                                                     u32* __restrict__ sfxBuf,
                                                     u32* __restrict__ cursor) {
  __shared__ u32 sfx[2048];
  int b = blockIdx.x;
  for (int t = threadIdx.x; t < 2048; t += 256) sfx[t] = hist[b * 2048 + t];
  __syncthreads();
  for (int d = 1; d < 2048; d <<= 1) {
    u32 v[8];
#pragma unroll
    for (int i = 0; i < 8; ++i) {
      int t = threadIdx.x + i * 256;
      v[i] = (t + d < 2048) ? sfx[t + d] : 0;
    }
    __syncthreads();
#pragma unroll
    for (int i = 0; i < 8; ++i) sfx[threadIdx.x + i * 256] += v[i];
    __syncthreads();
  }
  for (int t = threadIdx.x; t < 2048; t += 256) {
    u32 above = (t + 1 < 2048) ? sfx[t + 1] : 0;
    sfxBuf[b * 2048 + t] = sfx[t];
    cursor[b * 2048 + t] = above;                       // segment base
    if (above < PRE && sfx[t] >= PRE) { selinfo[b * 2] = (u32)t; selinfo[b * 2 + 1] = above; }
  }
}

// Compact: hi keys scatter directly into their bucket's segment of sel via
// per-bucket cursors (2048 addresses/batch -> low contention); mid keys go to
// the tie-break buffer. Within-segment order arbitrary; bsort fixes it.
__global__ __launch_bounds__(256) void compact_kernel(const u64* __restrict__ keys,
                                                      const u32* __restrict__ selinfo,
                                                      u32* __restrict__ cursor,
                                                      u64* __restrict__ sel, u64* __restrict__ mid,
                                                      u32* __restrict__ cnt_mid) {
  int g = blockIdx.x * 256 + threadIdx.x;
  int b = g >> 15;
  u64 key = keys[g];
  u32 bk = bucket_of(unorderable((u32)(key >> 32)));
  u32 T = selinfo[b * 2];
  if (bk > T) {
    u32 p = atomicAdd(&cursor[b * 2048 + bk], 1u);
    sel[((size_t)b << 12) + p] = key;
  } else if (bk == T) {
    u32 p = atomicAdd(&cnt_mid[b], 1u);
    if (p < MIDCAP) mid[(size_t)b * MIDCAP + p] = key;   // ~45 expected with this data
  }
}

// One wave per (batch, bucket). Buckets > T: in-register 64-lane bitonic sort
// of the segment (descending; zero-padding sinks). Bucket == T: pick the top
// (PRE-C1) mid keys by repeated wave argmax (fused midsel). Buckets < T: no-op.
__global__ __launch_bounds__(64) void bsort_kernel(u64* __restrict__ sel, u64* __restrict__ mid,
                                                   const u32* __restrict__ sfxBuf,
                                                   const u32* __restrict__ selinfo,
                                                   const u32* __restrict__ cnt_mid) {
  int t = blockIdx.x & 2047;
  int b = blockIdx.x >> 11;
  int lane = threadIdx.x;
  u32 T = selinfo[b * 2];
  u64* selB = sel + ((size_t)b << 12);
  if ((u32)t == T) {
    u32 C1 = selinfo[b * 2 + 1];
    int need = PRE - (int)C1;
    int M = (int)cnt_mid[b]; if (M > MIDCAP) M = MIDCAP;
    u64* midB = mid + (size_t)b * MIDCAP;
    for (int r = 0; r < need; ++r) {
      u64 best = 0; int bi = -1;
      for (int q = lane; q < M; q += 64) {
        u64 v = midB[q];
        if (v > best) { best = v; bi = q; }
      }
#pragma unroll
      for (int d = 32; d > 0; d >>= 1) {
        u64 ob = __shfl_xor(best, d, 64);
        int oi = __shfl_xor(bi, d, 64);
        if (ob > best) { best = ob; bi = oi; }
      }
      if (lane == 0) selB[C1 + r] = best;
      if (bi >= 0 && lane == (bi & 63)) midB[bi] = 0;    // remove chosen
    }
    return;
  }
  if ((u32)t < T) return;
  u32 start = (t < 2047) ? sfxBuf[b * 2048 + t + 1] : 0u;
  u32 end = sfxBuf[b * 2048 + t];
  int n = (int)(end - start);
  if (n <= 1) return;
  if (n <= 64) {
    u64 v = (lane < n) ? selB[start + lane] : 0ULL;      // real keys have MSB set -> pad sinks
#pragma unroll
    for (int k = 2; k <= 64; k <<= 1) {
#pragma unroll
      for (int j = k >> 1; j > 0; j >>= 1) {
        u64 o = __shfl_xor(v, j, 64);
        bool up = ((lane & k) == 0);                     // k=64 -> desc everywhere
        bool first = ((lane & j) == 0);
        u64 mx = v > o ? v : o, mn = v > o ? o : v;
        v = (first == up) ? mx : mn;
      }
    }
    if (lane < n) selB[start + lane] = v;
  } else {
    // robustness fallback (never hit on bench data): selection sort by wave argmax
    for (int r = 0; r < n - 1; ++r) {
      u64 best = 0; int bi = -1;
      for (int q = r + lane; q < n; q += 64) {
        u64 v = selB[start + q];
        if (v > best) { best = v; bi = q; }
      }
#pragma unroll
      for (int d = 32; d > 0; d >>= 1) {
        u64 ob = __shfl_xor(best, d, 64);
        int oi = __shfl_xor(bi, d, 64);
        if (ob > best) { best = ob; bi = oi; }
      }
      if (lane == 0) {
        u64 tmp = selB[start + r];
        selB[start + r] = best;
        selB[start + bi] = tmp;
      }
    }
  }
}

// Gather top-4096 boxes; pack bounds as float4 + area; recover score from key bits.
__global__ void gather_kernel(const u64* __restrict__ keys, const float* __restrict__ boxes,
                              const int* __restrict__ labels,
                              float* __restrict__ topBox, float4* __restrict__ P,
                              float* __restrict__ AR,
                              float* __restrict__ topS, int* __restrict__ topL) {
  int g = blockIdx.x * blockDim.x + threadIdx.x;
  if (g >= BB * PRE) return;
  int b = g >> 12;
  u64 key = keys[g];
  u32 n = ~(u32)key;
  size_t src = (size_t)b * NN + n;
  const float* bx = boxes + src * 7;
  float x = bx[0], y = bx[1], dx = bx[3], dy = bx[4];
  float* tb = topBox + (size_t)g * 7;
#pragma unroll
  for (int c = 0; c < 7; ++c) tb[c] = bx[c];
  float4 p;
  p.x = x - 0.5f * dx; p.z = x + 0.5f * dx;   // 0.5*dx exact -> contraction-safe
  p.y = y - 0.5f * dy; p.w = y + 0.5f * dy;
  P[g] = p;
  AR[g] = dx * dy;
  topS[g] = unorderable((u32)(key >> 32));
  topL[g] = labels[src];
}

// Suppression mask, lane=row, SCALAR-column form. ONE WAVE PER BLOCK so the
// tile coords (rb, w) are SGPR-uniform: the column box loads Pcol[k]/ARcol[k]
// inside the k-loop are wave-uniform addresses in uniform control flow ->
// compiler scalarizes to s_load (SMEM pipe), replacing 320 ds_bpermute/wave.
// Lane owns row rb*64+lane; mask word built in-register; word-major layout
// maskT[b][w][row] -> one coalesced 512B store per tile.
// Divide eliminated by inter > 0.7*denom with conservative marginal band;
// wave falls back to exact IEEE divide if any lane is in the band.
__global__ __launch_bounds__(64) void mask_kernel(const float4* __restrict__ P,
                                                  const float* __restrict__ AR,
                                                  u64* __restrict__ maskT,
                                                  u64* __restrict__ diag) {
  int b = blockIdx.y;
  int ti = blockIdx.x;                            // 2080 upper-tri tiles per batch
  int lane = threadIdx.x;
  // triangular decode: ti -> (rb, w), w >= rb (any bijection works)
  int u = 2079 - ti;
  int m = (int)((sqrtf(8.0f * (float)u + 1.0f) - 1.0f) * 0.5f);
  while ((m + 1) * (m + 2) / 2 <= u) ++m;         // uniform fixup
  while (m * (m + 1) / 2 > u) --m;
  int rb = 63 - m;
  int w = rb + (u - m * (m + 1) / 2);
  int base = b << 12;
  int row = (rb << 6) + lane;
  float4 rp = P[base + row];
  float rar = AR[base + row];
  const float4* __restrict__ Pcol = P + base + (w << 6);   // wave-uniform base
  const float* __restrict__ ARcol = AR + base + (w << 6);
  u64 bits = 0;
#pragma unroll
  for (int k = 0; k < 64; ++k) {
    float4 cb = Pcol[k];                           // uniform -> s_load_dwordx4
    float ca = ARcol[k];                           // uniform -> s_load_dword
    float ix = fminf(rp.z, cb.z) - fmaxf(rp.x, cb.x); ix = fmaxf(0.0f, ix);
    float iy = fminf(rp.w, cb.w) - fmaxf(rp.y, cb.y); iy = fmaxf(0.0f, iy);
    float inter = ix * iy;
    float denom = ((rar + ca) - inter) + 1e-6f;      // same op order as reference
    float t = 0.7f * denom;                          // denom >= 1 here, t > 0
    bool sup;
    bool marginal = fabsf(inter - t) <= 2e-5f * t;   // band >> max rounding skew (~4e-7)
    if (__any(marginal)) sup = (inter / denom) > NMS_TH;  // exact IEEE path
    else sup = inter > t;
    bits |= ((u64)(sup ? 1u : 0u)) << k;
  }
  maskT[((size_t)(b * 64 + w)) * PRE + row] = bits;  // coalesced 512B per tile
  if (w == rb) diag[base + row] = bits;
}

// Greedy scan, group-of-64 formulation. One wave per batch.
// Word-major mask: lane's row words are contiguous per group (512B run),
// loaded as 16B ulonglong2.
__global__ __launch_bounds__(64) void scan_kernel(const u64* __restrict__ maskT,
                                                  const u64* __restrict__ diag,
                                                  int* __restrict__ keepIdx,
                                                  int* __restrict__ keepCount) {
  __shared__ u64 kwLDS[64];
  int b = blockIdx.x;
  int lane = threadIdx.x;
  const u64* m = maskT + (size_t)b * 64 * PRE;
  const u64* dg = diag + (size_t)b * PRE;
  kwLDS[lane] = 0;
  __syncthreads();
  u64 r = 0;
  int nk = 0;
  for (int g = 0; g < PRE / 64; ++g) {
    u64 d_l = dg[g * 64 + lane];
    const ulonglong2* mp = (const ulonglong2*)(m + (size_t)lane * PRE + (g << 6));
    ulonglong2 rv[32];
#pragma unroll
    for (int q = 0; q < 32; ++q) rv[q] = mp[q];
    u64 sup_word = __shfl(r, g, 64);
    u64 keep_word = 0;
#pragma unroll
    for (int s = 0; s < 8; ++s) {
      u64 dk[8];
#pragma unroll
      for (int t = 0; t < 8; ++t) dk[t] = __shfl(d_l, s * 8 + t, 64);
#pragma unroll
      for (int t = 0; t < 8; ++t) {
        int k = s * 8 + t;
        u64 bit = (sup_word >> k) & 1ULL;
        keep_word |= (bit ^ 1ULL) << k;
        u64 mk = dk[t] & ~((2ULL << k) - 1ULL);
        sup_word |= mk & (bit - 1ULL);
      }
    }
    u64 acc = 0;
#pragma unroll
    for (int q = 0; q < 32; ++q) {
      acc |= ((keep_word >> (2 * q)) & 1ULL) ? rv[q].x : 0ULL;
      acc |= ((keep_word >> (2 * q + 1)) & 1ULL) ? rv[q].y : 0ULL;
    }
    r |= acc;
    if (lane == 0) kwLDS[g] = keep_word;
    nk += __popcll(keep_word);
    if (nk >= POST) break;
  }
  __syncthreads();
  u64 kw = kwLDS[lane];
  int cnt = __popcll(kw);
  int pfx = cnt;
#pragma unroll
  for (int d = 1; d < 64; d <<= 1) {
    int up = __shfl_up(pfx, d, 64);
    if (lane >= d) pfx += up;
  }
  int total = __shfl(pfx, 63, 64);
  int pos = pfx - cnt;
  while (kw) {
    int t = __ffsll((long long)kw) - 1;
    kw &= kw - 1;
    if (pos < POST) keepIdx[b * POST + pos] = lane * 64 + t;
    ++pos;
  }
  if (lane == 0) keepCount[b] = total < POST ? total : POST;
}

// Write all 512 slots per batch: kept -> data, empty -> 0 (label 1).
__global__ void output_kernel(const int* __restrict__ keepIdx, const int* __restrict__ keepCount,
                              const float* __restrict__ topBox, const float* __restrict__ topS,
                              const int* __restrict__ topL, float* __restrict__ out) {
  int g = blockIdx.x * blockDim.x + threadIdx.x;
  if (g >= BB * POST) return;
  int b = g >> 9, s = g & (POST - 1);
  float* outR = out;
  float* outS = out + BB * POST * 7;
  float* outL = outS + BB * POST;
  int cnt = keepCount[b];
  if (s < cnt) {
    int i = keepIdx[g];
    const float* tb = topBox + ((size_t)(b << 12) + i) * 7;
#pragma unroll
    for (int c = 0; c < 7; ++c) outR[(size_t)g * 7 + c] = tb[c];
    outS[g] = topS[(b << 12) + i];
    outL[g] = (float)(topL[(b << 12) + i] + 1);
  } else {
#pragma unroll
    for (int c = 0; c < 7; ++c) outR[(size_t)g * 7 + c] = 0.0f;
    outS[g] = 0.0f;
    outL[g] = 1.0f;
  }
}

extern "C" void kernel_launch(void* const* d_in, const int* in_sizes, int n_in,
                              void* d_out, int out_size, void* d_ws, size_t ws_size,
                              hipStream_t stream) {
  const float* boxes = (const float*)d_in[0];   // (4,32768,7)
  const float* cls   = (const float*)d_in[1];   // (4,32768,3)
  float* out = (float*)d_out;

  // ---- workspace carve-up (~11 MB) ----
  char* p = (char*)d_ws;
  auto take = [&](size_t bytes) { char* r = p; p += (bytes + 255) & ~(size_t)255; return (void*)r; };
  u64*   keys    = (u64*)  take((size_t)BB * NN * 8);
  int*   labels  = (int*)  take((size_t)BB * NN * 4);
  u32*   hist    = (u32*)  take((size_t)BB * 2048 * 4);
  u32*   selinfo = (u32*)  take((size_t)BB * 2 * 4);
  u32*   sfxBuf  = (u32*)  take((size_t)BB * 2048 * 4);
  u32*   cursor  = (u32*)  take((size_t)BB * 2048 * 4);
  u32*   cnt_mid = (u32*)  take((size_t)BB * 4);
  u64*   sel     = (u64*)  take((size_t)BB * PRE * 8);
  u64*   mid     = (u64*)  take((size_t)BB * MIDCAP * 8);
  float* topBox  = (float*)take((size_t)BB * PRE * 7 * 4);
  float4* Pb     = (float4*)take((size_t)BB * PRE * 16);
  float* AR      = (float*)take((size_t)BB * PRE * 4);
  float* topS    = (float*)take((size_t)BB * PRE * 4);
  int*   topL    = (int*)  take((size_t)BB * PRE * 4);
  u64*   maskT   = (u64*)  take((size_t)BB * 64 * PRE * 8);
  u64*   diagBuf = (u64*)  take((size_t)BB * PRE * 8);
  int*   keepIdx = (int*)  take((size_t)BB * POST * 4);
  int*   keepCnt = (int*)  take((size_t)BB * 4);

  zero_kernel<<<32, 256, 0, stream>>>(hist, cnt_mid);
  score_hist_kernel<<<BB * NN / 256, 256, 0, stream>>>(cls, labels, keys, hist);
  select_kernel<<<BB, 256, 0, stream>>>(hist, selinfo, sfxBuf, cursor);
  compact_kernel<<<BB * NN / 256, 256, 0, stream>>>(keys, selinfo, cursor, sel, mid, cnt_mid);
  bsort_kernel<<<BB * 2048, 64, 0, stream>>>(sel, mid, sfxBuf, selinfo, cnt_mid);
  gather_kernel<<<(BB * PRE + 255) / 256, 256, 0, stream>>>(sel, boxes, labels,
                                                            topBox, Pb, AR, topS, topL);
  mask_kernel<<<dim3(2080, BB), 64, 0, stream>>>(Pb, AR, maskT, diagBuf);
  scan_kernel<<<BB, 64, 0, stream>>>(maskT, diagBuf, keepIdx, keepCnt);
  output_kernel<<<(BB * POST + 255) / 256, 256, 0, stream>>>(keepIdx, keepCnt, topBox, topS, topL, out);
}